// Round 3
// baseline (82.925 us; speedup 1.0000x reference)
//
#include <hip/hip_runtime.h>
#include <hip/hip_cooperative_groups.h>

namespace cg = cooperative_groups;

typedef short short8 __attribute__((ext_vector_type(8)));
typedef float f32x4 __attribute__((ext_vector_type(4)));

static __device__ __forceinline__ unsigned short f2bf(float f) {
    unsigned u = __builtin_bit_cast(unsigned, f);
    u += 0x7FFFu + ((u >> 16) & 1u);   // RNE
    return (unsigned short)(u >> 16);
}

// ws layout:
//   [0,128K)    Btg  bf16, fragment-major: idx = ks*8192 + n16*512 + (n&15)*32 + ((k>>3)&3)*8 + (k&7)
//               (element (n,k) of Wp^T; a wave's (ks,n16) fragment = contiguous 1KB)
//   [128K,256K) injT bf16, fragment-major per b: idx = b*8192 + (col>>4)*512 + (col&15)*32 + (n>>3)*8 + (n&7)
//               (n = 16..31 zero-padded)
#define OFF_INJT (128 * 1024)

__global__ __launch_bounds__(256, 2)
void fused_coop(const float* __restrict__ patches,
                const float* __restrict__ embs,
                const int* __restrict__ locations,
                const float* __restrict__ Wp,
                const float* __restrict__ We,
                unsigned short* __restrict__ Btg,
                unsigned short* __restrict__ injT,
                float* __restrict__ out) {
    __shared__ float sh[64 * 65];
    __shared__ unsigned maskL[16];
    __shared__ float rcL[16];

    const int bid = blockIdx.x, t = threadIdx.x;
    const int b = bid >> 6, p0 = (bid & 63) * 16;
    const int wv = t >> 6, lane = t & 63, lhi = lane >> 4, llo = lane & 15;

    // ---- Phase A.1: issue this block's A-tile loads NOW (overlap with prep) ----
    const float* arow = patches + (size_t)(b * 1024 + p0 + llo) * 256;
    float4 a0[8], a1[8];
    #pragma unroll
    for (int ks = 0; ks < 8; ++ks) {
        a0[ks] = *reinterpret_cast<const float4*>(arow + ks * 32 + lhi * 8);
        a1[ks] = *reinterpret_cast<const float4*>(arow + ks * 32 + lhi * 8 + 4);
    }

    // ---- Phase A.2: per-block mask bits + 1/count for the 16 pixels ----
    if (t < 16) {
        int p = p0 + t;
        int h = p >> 5, w = p & 31;
        const int* loc = locations + b * 60;
        unsigned m = 1u << 15;  // full-image box always contains
        #pragma unroll
        for (int nb = 0; nb < 15; ++nb) {
            int y0 = loc[nb * 4 + 0] & ~1;
            int x0 = loc[nb * 4 + 1] & ~1;
            int y1 = (loc[nb * 4 + 2] & ~1) + 2;
            int x1 = (loc[nb * 4 + 3] & ~1) + 2;
            if (h >= y0 && h < y1 && w >= x0 && w < x1) m |= 1u << nb;
        }
        maskL[t] = m;
        rcL[t] = 1.0f / (float)__popc(m);
    }

    // ---- Phase A.3: distributed prep ----
    if (bid < 128) {
        // inj row (b2, n): (embs_ext[b2] @ We)[n, :] -> injT (fragment-major bf16)
        const int b2 = bid >> 4, n = bid & 15;
        float e;
        if (n == 15) {
            float s = 0.f;
            #pragma unroll
            for (int j = 0; j < 15; ++j) s += embs[(b2 * 15 + j) * 256 + t];
            e = s * (1.0f / 15.0f);
        } else {
            e = embs[(b2 * 15 + n) * 256 + t];
        }
        sh[t] = e;
        __syncthreads();
        float s0 = 0.f, s1 = 0.f, s2 = 0.f, s3 = 0.f;
        #pragma unroll 8
        for (int k0 = 0; k0 < 256; k0 += 4) {
            float4 e4 = *reinterpret_cast<const float4*>(&sh[k0]);
            s0 += e4.x * We[(k0 + 0) * 256 + t];
            s1 += e4.y * We[(k0 + 1) * 256 + t];
            s2 += e4.z * We[(k0 + 2) * 256 + t];
            s3 += e4.w * We[(k0 + 3) * 256 + t];
        }
        float acc = (s0 + s1) + (s2 + s3);
        int base = b2 * 8192 + (t >> 4) * 512 + (t & 15) * 32;
        injT[base + (n >> 3) * 8 + (n & 7)] = f2bf(acc);
        if (n == 15) {  // zero pad n=16..31
            uint4 z = {0, 0, 0, 0};
            *reinterpret_cast<uint4*>(&injT[base + 16]) = z;
            *reinterpret_cast<uint4*>(&injT[base + 24]) = z;
        }
    } else if (bid < 144) {
        // 64x64 transpose tile of Wp -> Btg (fragment-major bf16)
        const int tt = bid - 128;
        const int kt = (tt >> 2) * 64, n0 = (tt & 3) * 64;
        #pragma unroll
        for (int it = 0; it < 16; ++it) {
            int u = t + it * 256;
            int kl = u >> 6, nl = u & 63;
            sh[kl * 65 + nl] = Wp[(kt + kl) * 256 + n0 + nl];
        }
        __syncthreads();
        #pragma unroll
        for (int it = 0; it < 4; ++it) {
            int v = t + it * 256;
            int nl = v >> 4, kg = v & 15;   // k = kt + kg*4 + c
            ushort4 o;
            o.x = f2bf(sh[(kg * 4 + 0) * 65 + nl]);
            o.y = f2bf(sh[(kg * 4 + 1) * 65 + nl]);
            o.z = f2bf(sh[(kg * 4 + 2) * 65 + nl]);
            o.w = f2bf(sh[(kg * 4 + 3) * 65 + nl]);
            int ks = (kt >> 5) + (kg >> 3);
            int n16 = (n0 >> 4) + (nl >> 4);
            int idx = ks * 8192 + n16 * 512 + (nl & 15) * 32 + ((kg >> 1) & 3) * 8 + (kg & 1) * 4;
            *reinterpret_cast<ushort4*>(&Btg[idx]) = o;
        }
    }

    // ---- Phase A.4: pack A-tile f32 -> bf16 fragments ----
    short8 af[8];
    #pragma unroll
    for (int ks = 0; ks < 8; ++ks) {
        short8 a;
        a[0] = (short)f2bf(a0[ks].x); a[1] = (short)f2bf(a0[ks].y);
        a[2] = (short)f2bf(a0[ks].z); a[3] = (short)f2bf(a0[ks].w);
        a[4] = (short)f2bf(a1[ks].x); a[5] = (short)f2bf(a1[ks].y);
        a[6] = (short)f2bf(a1[ks].z); a[7] = (short)f2bf(a1[ks].w);
        af[ks] = a;
    }

    cg::this_grid().sync();

    // ---- Phase B: proj GEMM, fully coalesced fragment loads ----
    f32x4 acc[4];
    #pragma unroll
    for (int nt = 0; nt < 4; ++nt) acc[nt] = (f32x4){0.f, 0.f, 0.f, 0.f};

    #pragma unroll
    for (int ks = 0; ks < 8; ++ks) {
        #pragma unroll
        for (int nt = 0; nt < 4; ++nt) {
            const short8 bf = *reinterpret_cast<const short8*>(
                Btg + ks * 8192 + (wv * 4 + nt) * 512 + llo * 32 + lhi * 8);
            acc[nt] = __builtin_amdgcn_mfma_f32_16x16x32_bf16(af[ks], bf, acc[nt], 0, 0, 0);
        }
    }

    // ---- epilogue: pooled masked-inj via one MFMA layer ----
    unsigned m = maskL[llo];
    short8 mfrag;
    #pragma unroll
    for (int r = 0; r < 8; ++r) {
        int k = lhi * 8 + r;
        mfrag[r] = (k < 16 && ((m >> k) & 1u)) ? (short)0x3F80 : (short)0;
    }
    f32x4 accE[4];
    #pragma unroll
    for (int nt = 0; nt < 4; ++nt) {
        const short8 jf = *reinterpret_cast<const short8*>(
            injT + b * 8192 + (wv * 4 + nt) * 512 + llo * 32 + lhi * 8);
        accE[nt] = __builtin_amdgcn_mfma_f32_16x16x32_bf16(
            mfrag, jf, (f32x4){0.f, 0.f, 0.f, 0.f}, 0, 0, 0);
    }

    float rc[4];
    #pragma unroll
    for (int j = 0; j < 4; ++j) rc[j] = rcL[lhi * 4 + j];

    float* ob = out + ((size_t)b * 1024 + p0) * 256;
    #pragma unroll
    for (int nt = 0; nt < 4; ++nt)
        #pragma unroll
        for (int j = 0; j < 4; ++j)
            ob[(lhi * 4 + j) * 256 + wv * 64 + nt * 16 + llo] = acc[nt][j] + rc[j] * accE[nt][j];
}

extern "C" void kernel_launch(void* const* d_in, const int* in_sizes, int n_in,
                              void* d_out, int out_size, void* d_ws, size_t ws_size,
                              hipStream_t stream) {
    const float* patches = (const float*)d_in[0];
    const float* embs    = (const float*)d_in[1];
    const int*   locs    = (const int*)d_in[2];
    const float* Wp      = (const float*)d_in[3];
    const float* We      = (const float*)d_in[4];
    float* out = (float*)d_out;

    unsigned short* Btg  = (unsigned short*)d_ws;
    unsigned short* injT = (unsigned short*)((char*)d_ws + OFF_INJT);

    void* args[] = {(void*)&patches, (void*)&embs, (void*)&locs, (void*)&Wp,
                    (void*)&We, (void*)&Btg, (void*)&injT, (void*)&out};
    hipLaunchCooperativeKernel((const void*)fused_coop, dim3(512), dim3(256),
                               args, 0, stream);
}

// Round 4
// 20.289 us; speedup vs baseline: 4.0872x; 4.0872x over previous
//
#include <hip/hip_runtime.h>

typedef short short8 __attribute__((ext_vector_type(8)));
typedef float f32x4 __attribute__((ext_vector_type(4)));

static __device__ __forceinline__ unsigned short f2bf(float f) {
    unsigned u = __builtin_bit_cast(unsigned, f);
    u += 0x7FFFu + ((u >> 16) & 1u);   // RNE
    return (unsigned short)(u >> 16);
}

// ws layout (fragment-major, verified in round 3):
//   [0,128K)    Btg  bf16: element (n,k) of Wp^T at
//               idx = (k>>5)*8192 + (n>>4)*512 + (n&15)*32 + (k&31)
//               -> a wave's (ks,n16) fragment load (llo*32+lhi*8) is 1KB contiguous
//   [128K,256K) injT bf16 per b: element (col,n) at
//               idx = b*8192 + (col>>4)*512 + (col&15)*32 + n     (n=16..31 zero)
#define OFF_INJT (128 * 1024)

// Prep: blocks 0..127 -> inj row (b,n) -> injT ; blocks 128..143 -> Wp^T -> Btg
__global__ __launch_bounds__(256)
void prep_kernel(const float* __restrict__ embs,
                 const float* __restrict__ Wp,
                 const float* __restrict__ We,
                 unsigned short* __restrict__ Btg,
                 unsigned short* __restrict__ injT) {
    __shared__ float sh[64 * 65];
    const int bid = blockIdx.x, t = threadIdx.x;
    if (bid < 128) {
        const int b = bid >> 4, n = bid & 15;
        float e;
        if (n == 15) {
            float s = 0.f;
            #pragma unroll
            for (int j = 0; j < 15; ++j) s += embs[(b * 15 + j) * 256 + t];
            e = s * (1.0f / 15.0f);
        } else {
            e = embs[(b * 15 + n) * 256 + t];
        }
        sh[t] = e;
        __syncthreads();
        float s0 = 0.f, s1 = 0.f, s2 = 0.f, s3 = 0.f;
        #pragma unroll 8
        for (int k0 = 0; k0 < 256; k0 += 4) {
            float4 e4 = *reinterpret_cast<const float4*>(&sh[k0]);
            s0 += e4.x * We[(k0 + 0) * 256 + t];
            s1 += e4.y * We[(k0 + 1) * 256 + t];
            s2 += e4.z * We[(k0 + 2) * 256 + t];
            s3 += e4.w * We[(k0 + 3) * 256 + t];
        }
        float acc = (s0 + s1) + (s2 + s3);
        int base = b * 8192 + (t >> 4) * 512 + (t & 15) * 32;
        injT[base + n] = f2bf(acc);
        if (n == 15) {  // zero pad n=16..31
            uint4 z = {0, 0, 0, 0};
            *reinterpret_cast<uint4*>(&injT[base + 16]) = z;
            *reinterpret_cast<uint4*>(&injT[base + 24]) = z;
        }
    } else {
        // 64x64 transpose tile of Wp -> Btg (fragment-major bf16)
        const int tt = bid - 128;
        const int kt = (tt >> 2) * 64, n0 = (tt & 3) * 64;
        #pragma unroll
        for (int it = 0; it < 16; ++it) {
            int u = t + it * 256;
            int kl = u >> 6, nl = u & 63;
            sh[kl * 65 + nl] = Wp[(kt + kl) * 256 + n0 + nl];
        }
        __syncthreads();
        #pragma unroll
        for (int it = 0; it < 4; ++it) {
            int v = t + it * 256;
            int nl = v >> 4, kg = v & 15;   // k = kt + kg*4 + c, c = 0..3
            ushort4 o;
            o.x = f2bf(sh[(kg * 4 + 0) * 65 + nl]);
            o.y = f2bf(sh[(kg * 4 + 1) * 65 + nl]);
            o.z = f2bf(sh[(kg * 4 + 2) * 65 + nl]);
            o.w = f2bf(sh[(kg * 4 + 3) * 65 + nl]);
            int ks = (kt >> 5) + (kg >> 3);
            int n16 = (n0 >> 4) + (nl >> 4);
            int idx = ks * 8192 + n16 * 512 + (nl & 15) * 32 + ((kg >> 1) & 3) * 8 + (kg & 1) * 4;
            *reinterpret_cast<ushort4*>(&Btg[idx]) = o;
        }
    }
}

// Fused: block = (b, 16-pixel tile) x 256 cols, 4 waves. No LDS staging of A/B,
// no barriers in the hot path; all global loads coalesced.
__global__ __launch_bounds__(256)
void fused_kernel(const float* __restrict__ patches,
                  const int* __restrict__ locations,
                  const unsigned short* __restrict__ Btg,
                  const unsigned short* __restrict__ injT,
                  float* __restrict__ out) {
    __shared__ unsigned maskL[16];
    __shared__ float rcL[16];

    const int bid = blockIdx.x, t = threadIdx.x;
    const int b = bid >> 6, p0 = (bid & 63) * 16;
    const int wv = t >> 6, lane = t & 63, lhi = lane >> 4, llo = lane & 15;

    // masks for the 16 pixels (tiny divergent section, one barrier at the end)
    if (t < 16) {
        int p = p0 + t;
        int h = p >> 5, w = p & 31;
        const int* loc = locations + b * 60;
        unsigned m = 1u << 15;  // full-image box always contains
        #pragma unroll
        for (int nb = 0; nb < 15; ++nb) {
            int y0 = loc[nb * 4 + 0] & ~1;
            int x0 = loc[nb * 4 + 1] & ~1;
            int y1 = (loc[nb * 4 + 2] & ~1) + 2;
            int x1 = (loc[nb * 4 + 3] & ~1) + 2;
            if (h >= y0 && h < y1 && w >= x0 && w < x1) m |= 1u << nb;
        }
        maskL[t] = m;
        rcL[t] = 1.0f / (float)__popc(m);
    }

    // A fragments straight from HBM: row p0+llo, k = ks*32 + lhi*8 (+0..7)
    const float* arow = patches + (size_t)(b * 1024 + p0 + llo) * 256;
    float4 a0[8], a1[8];
    #pragma unroll
    for (int ks = 0; ks < 8; ++ks) {
        a0[ks] = *reinterpret_cast<const float4*>(arow + ks * 32 + lhi * 8);
        a1[ks] = *reinterpret_cast<const float4*>(arow + ks * 32 + lhi * 8 + 4);
    }
    short8 af[8];
    #pragma unroll
    for (int ks = 0; ks < 8; ++ks) {
        short8 a;
        a[0] = (short)f2bf(a0[ks].x); a[1] = (short)f2bf(a0[ks].y);
        a[2] = (short)f2bf(a0[ks].z); a[3] = (short)f2bf(a0[ks].w);
        a[4] = (short)f2bf(a1[ks].x); a[5] = (short)f2bf(a1[ks].y);
        a[6] = (short)f2bf(a1[ks].z); a[7] = (short)f2bf(a1[ks].w);
        af[ks] = a;
    }

    // proj GEMM: B fragment loads are 1KB contiguous per wave (L2-resident)
    f32x4 acc[4];
    #pragma unroll
    for (int nt = 0; nt < 4; ++nt) acc[nt] = (f32x4){0.f, 0.f, 0.f, 0.f};
    #pragma unroll
    for (int ks = 0; ks < 8; ++ks) {
        #pragma unroll
        for (int nt = 0; nt < 4; ++nt) {
            const short8 bf = *reinterpret_cast<const short8*>(
                Btg + ks * 8192 + (wv * 4 + nt) * 512 + llo * 32 + lhi * 8);
            acc[nt] = __builtin_amdgcn_mfma_f32_16x16x32_bf16(af[ks], bf, acc[nt], 0, 0, 0);
        }
    }

    __syncthreads();  // maskL/rcL ready (waves long since diverged past the write)

    // epilogue: pooled masked-inj via one MFMA layer
    unsigned m = maskL[llo];
    short8 mfrag;
    #pragma unroll
    for (int r = 0; r < 8; ++r) {
        int k = lhi * 8 + r;
        mfrag[r] = (k < 16 && ((m >> k) & 1u)) ? (short)0x3F80 : (short)0;
    }
    f32x4 accE[4];
    #pragma unroll
    for (int nt = 0; nt < 4; ++nt) {
        const short8 jf = *reinterpret_cast<const short8*>(
            injT + b * 8192 + (wv * 4 + nt) * 512 + llo * 32 + lhi * 8);
        accE[nt] = __builtin_amdgcn_mfma_f32_16x16x32_bf16(
            mfrag, jf, (f32x4){0.f, 0.f, 0.f, 0.f}, 0, 0, 0);
    }

    float rc[4];
    #pragma unroll
    for (int j = 0; j < 4; ++j) rc[j] = rcL[lhi * 4 + j];

    float* ob = out + ((size_t)b * 1024 + p0) * 256;
    #pragma unroll
    for (int nt = 0; nt < 4; ++nt)
        #pragma unroll
        for (int j = 0; j < 4; ++j)
            ob[(lhi * 4 + j) * 256 + wv * 64 + nt * 16 + llo] = acc[nt][j] + rc[j] * accE[nt][j];
}

extern "C" void kernel_launch(void* const* d_in, const int* in_sizes, int n_in,
                              void* d_out, int out_size, void* d_ws, size_t ws_size,
                              hipStream_t stream) {
    const float* patches = (const float*)d_in[0];
    const float* embs    = (const float*)d_in[1];
    const int*   locs    = (const int*)d_in[2];
    const float* Wp      = (const float*)d_in[3];
    const float* We      = (const float*)d_in[4];
    float* out = (float*)d_out;

    unsigned short* Btg  = (unsigned short*)d_ws;
    unsigned short* injT = (unsigned short*)((char*)d_ws + OFF_INJT);

    prep_kernel<<<144, 256, 0, stream>>>(embs, Wp, We, Btg, injT);
    fused_kernel<<<512, 256, 0, stream>>>(patches, locs, Btg, injT, out);
}